// Round 1
// baseline (2142.588 us; speedup 1.0000x reference)
//
#include <hip/hip_runtime.h>
#include <stdint.h>

typedef __attribute__((ext_vector_type(8))) short bf16x8;
typedef __attribute__((ext_vector_type(4))) short short4v;
typedef __attribute__((ext_vector_type(4))) float f32x4;

#define NB   2
#define CCH  256
#define PSP  65536
#define NTOK 131072

static __device__ __forceinline__ short f2bf(float f) {
  union { float f; uint32_t u; } v; v.f = f;
  uint32_t r = (v.u + 0x7FFFu + ((v.u >> 16) & 1u)) >> 16;
  return (short)(uint16_t)r;
}

// ---------------- weight fp32 -> bf16 ----------------
__global__ __launch_bounds__(256) void k_cvt_w(const float* __restrict__ src,
                                               short* __restrict__ dst, int n) {
  int i = (blockIdx.x * 256 + threadIdx.x) * 4;
  if (i + 3 < n) {
    f32x4 v = *(const f32x4*)(src + i);
    short4v o;
    o[0] = f2bf(v[0]); o[1] = f2bf(v[1]); o[2] = f2bf(v[2]); o[3] = f2bf(v[3]);
    *(short4v*)(dst + i) = o;
  }
}

// ---------------- x[b][c][p] fp32 -> h[b][p][c] bf16 ----------------
__global__ __launch_bounds__(256) void k_tin(const float* __restrict__ x,
                                             short* __restrict__ hb) {
  __shared__ float tile[64][65];
  int p0 = blockIdx.x * 64, c0 = blockIdx.y * 64, b = blockIdx.z;
  int tx = threadIdx.x & 63, tr = threadIdx.x >> 6;
  const float* xp = x + ((size_t)b * CCH + c0) * PSP + p0;
  #pragma unroll
  for (int it = 0; it < 16; ++it) {
    int c = it * 4 + tr;
    tile[c][tx] = xp[(size_t)c * PSP + tx];
  }
  __syncthreads();
  short* hp = hb + ((size_t)b * PSP + p0) * CCH + c0;
  #pragma unroll
  for (int it = 0; it < 16; ++it) {
    int p = it * 4 + tr;
    hp[(size_t)p * CCH + tx] = f2bf(tile[tx][p]);
  }
}

// ---------------- fused QKV projection GEMM (token-major) ----------------
// D^T orientation: A = W rows (co), B = H^T cols (tok). C/D: col=lane&15 (tok),
// row=(lane>>4)*4+reg (co) -> each lane stores 4 consecutive co as one 8B chunk.
__global__ __launch_bounds__(256) void k_qkv(const short* __restrict__ hb,
    const short* __restrict__ wq, const short* __restrict__ wk,
    const short* __restrict__ wv,
    short* __restrict__ qb, short* __restrict__ kb, short* __restrict__ vb)
{
  __shared__ short ht[64 * 256];
  int tid = threadIdx.x;
  int lane = tid & 63;
  int w = tid >> 6;
  int g = lane >> 4;
  int lm = lane & 15;
  size_t wgtok = (size_t)blockIdx.x * 64;
  const short* src = hb + wgtok * 256;
  // stage 64 tok x 256 c, XOR-swizzled in 16B units within each 512B row
  #pragma unroll
  for (int it = 0; it < 8; ++it) {
    int slot = it * 256 + tid;
    int row = slot >> 5;
    int cu  = slot & 31;
    bf16x8 v = *(const bf16x8*)(src + row * 256 + cu * 8);
    int su = cu ^ (row & 7);
    *(bf16x8*)(ht + row * 256 + su * 8) = v;
  }
  __syncthreads();

  int myrow = w * 16 + lm;  // tok row within tile (B col index)
  const short* wmat[3] = {wq, wk, wv};
  short* omat[3] = {qb, kb, vb};
  #pragma unroll
  for (int m = 0; m < 3; ++m) {
    const short* W = wmat[m];
    f32x4 acc[16];
    #pragma unroll
    for (int i = 0; i < 16; ++i) { acc[i][0]=0.f; acc[i][1]=0.f; acc[i][2]=0.f; acc[i][3]=0.f; }
    #pragma unroll
    for (int ks = 0; ks < 8; ++ks) {
      int unit = (ks * 4 + g) ^ (myrow & 7);
      bf16x8 bfrag = *(const bf16x8*)(ht + myrow * 256 + unit * 8);
      #pragma unroll
      for (int i = 0; i < 16; ++i) {
        bf16x8 afrag = *(const bf16x8*)(W + (size_t)(i * 16 + lm) * 256 + ks * 32 + g * 8);
        acc[i] = __builtin_amdgcn_mfma_f32_16x16x32_bf16(afrag, bfrag, acc[i], 0, 0, 0);
      }
    }
    short* dst = omat[m] + (wgtok + myrow) * 256;
    #pragma unroll
    for (int i = 0; i < 16; ++i) {
      short4v o;
      o[0] = f2bf(acc[i][0]); o[1] = f2bf(acc[i][1]);
      o[2] = f2bf(acc[i][2]); o[3] = f2bf(acc[i][3]);
      *(short4v*)(dst + i * 16 + g * 4) = o;
    }
  }
}

// ---------------- fused attention + output projection ----------------
// One block = one sequence; wave = head (L=64: each wave full seq; L=16 same).
// T = K Q^T (swapped) -> softmax over rows of T is lane-local + 2 shuffles.
// P packed in-register with k-permutation m = 32ks + 16*(j>>2) + 4g + (j&3),
// V B-frags read from LDS with the same permutation (valid for any shared map).
template<int L>
__global__ __launch_bounds__(256) void k_att(const short* __restrict__ qb,
    const short* __restrict__ kb, const short* __restrict__ vb,
    const short* __restrict__ wo, float* __restrict__ accb,
    int mulA, int mulB, int stride, int first)
{
  constexpr int NI = L / 16;
  constexpr int KS = (L == 64) ? 2 : 1;
  constexpr int VBYTES = 4 * L * 72 * 2;
  constexpr int OBYTES = L * 264 * 2;
  __shared__ char lds[(VBYTES > OBYTES) ? VBYTES : OBYTES];

  int tid = threadIdx.x, lane = tid & 63, w = tid >> 6, g = lane >> 4, lm = lane & 15;
  int s = blockIdx.x, b = blockIdx.y;
  size_t base = (size_t)b * PSP + (size_t)(s >> 6) * mulA + (size_t)(s & 63) * mulB;

  short* vw = (short*)lds + w * L * 72;  // this wave's V tile [L][72]
  // ---- stage V (per head) ----
  if (L == 64) {
    const short* vrow = vb + (base + (size_t)lane * stride) * 256 + w * 64;
    #pragma unroll
    for (int j = 0; j < 8; ++j)
      *(bf16x8*)&vw[lane * 72 + j * 8] = *(const bf16x8*)(vrow + j * 8);
  } else {
    const short* vrow = vb + (base + (size_t)lm * stride) * 256 + w * 64 + g * 16;
    #pragma unroll
    for (int j = 0; j < 2; ++j)
      *(bf16x8*)&vw[lm * 72 + g * 16 + j * 8] = *(const bf16x8*)(vrow + j * 8);
  }
  __syncthreads();

  // ---- T = K Q^T ----
  const short* qh = qb + base * 256 + w * 64;
  const short* kh = kb + base * 256 + w * 64;
  f32x4 t[NI][NI];
  #pragma unroll
  for (int i = 0; i < NI; ++i)
    #pragma unroll
    for (int j = 0; j < NI; ++j) { t[i][j][0]=0.f; t[i][j][1]=0.f; t[i][j][2]=0.f; t[i][j][3]=0.f; }
  #pragma unroll
  for (int ks = 0; ks < 2; ++ks) {
    bf16x8 af[NI], bq[NI];
    #pragma unroll
    for (int i = 0; i < NI; ++i)
      af[i] = *(const bf16x8*)(kh + (size_t)(i * 16 + lm) * stride * 256 + ks * 32 + g * 8);
    #pragma unroll
    for (int i = 0; i < NI; ++i)
      bq[i] = *(const bf16x8*)(qh + (size_t)(i * 16 + lm) * stride * 256 + ks * 32 + g * 8);
    #pragma unroll
    for (int mi = 0; mi < NI; ++mi)
      #pragma unroll
      for (int lj = 0; lj < NI; ++lj)
        t[mi][lj] = __builtin_amdgcn_mfma_f32_16x16x32_bf16(af[mi], bq[lj], t[mi][lj], 0, 0, 0);
  }

  // ---- softmax over m (rows of T), per column lj ----
  const float fac = 0.18033688011112042f;  // (1/8) * log2(e)
  float inv[NI];
  #pragma unroll
  for (int lj = 0; lj < NI; ++lj) {
    float mx = -3.0e38f;
    #pragma unroll
    for (int mi = 0; mi < NI; ++mi)
      #pragma unroll
      for (int r = 0; r < 4; ++r) mx = fmaxf(mx, t[mi][lj][r]);
    mx = fmaxf(mx, __shfl_xor(mx, 16));
    mx = fmaxf(mx, __shfl_xor(mx, 32));
    float sm = 0.f;
    #pragma unroll
    for (int mi = 0; mi < NI; ++mi)
      #pragma unroll
      for (int r = 0; r < 4; ++r) {
        float e = exp2f((t[mi][lj][r] - mx) * fac);
        t[mi][lj][r] = e; sm += e;
      }
    sm += __shfl_xor(sm, 16);
    sm += __shfl_xor(sm, 32);
    inv[lj] = 1.0f / sm;
  }

  // ---- pack P into permuted-k A fragments ----
  bf16x8 pa[NI][KS];
  #pragma unroll
  for (int lj = 0; lj < NI; ++lj)
    #pragma unroll
    for (int ks = 0; ks < KS; ++ks) {
      bf16x8 a;
      #pragma unroll
      for (int j = 0; j < 8; ++j) {
        int mi = ks * 2 + (j >> 2);
        float v = (mi < NI) ? t[mi][lj][j & 3] * inv[lj] : 0.f;
        a[j] = f2bf(v);
      }
      pa[lj][ks] = a;
    }

  // ---- O = P V ----
  f32x4 oa[NI][4];
  #pragma unroll
  for (int i = 0; i < NI; ++i)
    #pragma unroll
    for (int j = 0; j < 4; ++j) { oa[i][j][0]=0.f; oa[i][j][1]=0.f; oa[i][j][2]=0.f; oa[i][j][3]=0.f; }
  #pragma unroll
  for (int ks = 0; ks < KS; ++ks)
    #pragma unroll
    for (int ej = 0; ej < 4; ++ej) {
      bf16x8 bv;
      int e = ej * 16 + lm;
      int rb = ks * 32 + g * 4;
      #pragma unroll
      for (int j = 0; j < 4; ++j) bv[j] = vw[(rb + j) * 72 + e];
      if (L == 64) {
        #pragma unroll
        for (int j = 0; j < 4; ++j) bv[4 + j] = vw[(rb + 16 + j) * 72 + e];
      } else {
        #pragma unroll
        for (int j = 0; j < 4; ++j) bv[4 + j] = 0;
      }
      #pragma unroll
      for (int lj = 0; lj < NI; ++lj)
        oa[lj][ej] = __builtin_amdgcn_mfma_f32_16x16x32_bf16(pa[lj][ks], bv, oa[lj][ej], 0, 0, 0);
    }

  __syncthreads();  // done with V region; alias as o_tile
  short* ot = (short*)lds;  // [L][264]
  #pragma unroll
  for (int lj = 0; lj < NI; ++lj)
    #pragma unroll
    for (int ej = 0; ej < 4; ++ej)
      #pragma unroll
      for (int r = 0; r < 4; ++r)
        ot[(lj * 16 + g * 4 + r) * 264 + w * 64 + ej * 16 + lm] = f2bf(oa[lj][ej][r]);
  __syncthreads();

  // ---- output projection: D^T, A = Wo rows (co), B = o_tile^T cols (tok) ----
  constexpr int NIF = (L == 64) ? 16 : 4;
  int if0 = (L == 64) ? 0 : (w * 4);
  int tw  = (L == 64) ? (w * 16) : 0;
  f32x4 pacc[NIF];
  #pragma unroll
  for (int i = 0; i < NIF; ++i) { pacc[i][0]=0.f; pacc[i][1]=0.f; pacc[i][2]=0.f; pacc[i][3]=0.f; }
  #pragma unroll
  for (int ks = 0; ks < 8; ++ks) {
    bf16x8 bo_ = *(const bf16x8*)&ot[(tw + lm) * 264 + ks * 32 + g * 8];
    #pragma unroll
    for (int i = 0; i < NIF; ++i) {
      bf16x8 af = *(const bf16x8*)(wo + (size_t)((if0 + i) * 16 + lm) * 256 + ks * 32 + g * 8);
      pacc[i] = __builtin_amdgcn_mfma_f32_16x16x32_bf16(af, bo_, pacc[i], 0, 0, 0);
    }
  }
  size_t tokr = base + (size_t)(tw + lm) * stride;
  float* dst0 = accb + tokr * 256;
  #pragma unroll
  for (int i = 0; i < NIF; ++i) {
    int co = (if0 + i) * 16 + g * 4;
    f32x4* dp = (f32x4*)(dst0 + co);
    if (first) {
      *dp = pacc[i];
    } else {
      f32x4 old = *dp;
      old[0] += pacc[i][0]; old[1] += pacc[i][1];
      old[2] += pacc[i][2]; old[3] += pacc[i][3];
      *dp = old;
    }
  }
}

// ---------------- acc[b][p][c] fp32 (+ Σbias) -> out[b][c][p] fp32 ----------------
__global__ __launch_bounds__(256) void k_final(const float* __restrict__ acc,
                                               const float* __restrict__ bo,
                                               float* __restrict__ out) {
  __shared__ float tile[64][65];
  __shared__ float bias[64];
  int p0 = blockIdx.x * 64, c0 = blockIdx.y * 64, b = blockIdx.z;
  int tx = threadIdx.x & 63, tr = threadIdx.x >> 6;
  if (threadIdx.x < 64)
    bias[threadIdx.x] = bo[c0 + threadIdx.x] + bo[256 + c0 + threadIdx.x] + bo[512 + c0 + threadIdx.x];
  const float* ap = acc + ((size_t)b * PSP + p0) * CCH + c0;
  #pragma unroll
  for (int it = 0; it < 16; ++it) {
    int p = it * 4 + tr;
    tile[tx][p] = ap[(size_t)p * CCH + tx];
  }
  __syncthreads();
  float* op = out + ((size_t)b * CCH + c0) * PSP + p0;
  #pragma unroll
  for (int it = 0; it < 16; ++it) {
    int c = it * 4 + tr;
    op[(size_t)c * PSP + tx] = tile[c][tx] + bias[c];
  }
}

extern "C" void kernel_launch(void* const* d_in, const int* in_sizes, int n_in,
                              void* d_out, int out_size, void* d_ws, size_t ws_size,
                              hipStream_t stream) {
  const float* x  = (const float*)d_in[0];
  const float* Wq = (const float*)d_in[1];
  const float* Wk = (const float*)d_in[2];
  const float* Wv = (const float*)d_in[3];
  const float* Wo = (const float*)d_in[4];
  const float* bo = (const float*)d_in[5];
  float* out = (float*)d_out;

  char* ws = (char*)d_ws;
  size_t off = 0;
  auto alloc = [&](size_t bytes) -> char* {
    char* p = ws + off;
    off += (bytes + 255) & ~(size_t)255;
    return p;
  };
  short* wqb  = (short*)alloc((size_t)3 * 65536 * 2);
  short* wkb  = (short*)alloc((size_t)3 * 65536 * 2);
  short* wvb  = (short*)alloc((size_t)3 * 65536 * 2);
  short* wob  = (short*)alloc((size_t)3 * 65536 * 2);
  short* hb   = (short*)alloc((size_t)NTOK * 256 * 2);
  short* qbuf = (short*)alloc((size_t)NTOK * 256 * 2);
  short* kbuf = (short*)alloc((size_t)NTOK * 256 * 2);
  short* vbuf = (short*)alloc((size_t)NTOK * 256 * 2);
  float* accb = (float*)alloc((size_t)NTOK * 256 * 4);
  if (off > ws_size) return;  // workspace too small: bail (output will mismatch)

  k_cvt_w<<<192, 256, 0, stream>>>(Wq, wqb, 196608);
  k_cvt_w<<<192, 256, 0, stream>>>(Wk, wkb, 196608);
  k_cvt_w<<<192, 256, 0, stream>>>(Wv, wvb, 196608);
  k_cvt_w<<<192, 256, 0, stream>>>(Wo, wob, 196608);
  k_tin<<<dim3(1024, 4, 2), 256, 0, stream>>>(x, hb);

  for (int ax = 0; ax < 3; ++ax) {
    k_qkv<<<2048, 256, 0, stream>>>(hb, wqb + ax * 65536, wkb + ax * 65536,
                                    wvb + ax * 65536, qbuf, kbuf, vbuf);
    if (ax == 0)
      k_att<16><<<dim3(4096, 2), 256, 0, stream>>>(qbuf, kbuf, vbuf, wob, accb,
                                                   64, 1, 4096, 1);
    else if (ax == 1)
      k_att<64><<<dim3(1024, 2), 256, 0, stream>>>(qbuf, kbuf, vbuf, wob + 65536, accb,
                                                   4096, 1, 64, 0);
    else
      k_att<64><<<dim3(1024, 2), 256, 0, stream>>>(qbuf, kbuf, vbuf, wob + 131072, accb,
                                                   4096, 64, 1, 0);
  }
  k_final<<<dim3(1024, 4, 2), 256, 0, stream>>>(accb, bo, out);
}

// Round 3
// 1107.484 us; speedup vs baseline: 1.9346x; 1.9346x over previous
//
#include <hip/hip_runtime.h>
#include <stdint.h>

typedef __attribute__((ext_vector_type(8))) short bf16x8;
typedef __attribute__((ext_vector_type(4))) short short4v;
typedef __attribute__((ext_vector_type(4))) float f32x4;

#define CCH  256
#define PSP  65536
#define NTOK 131072

static __device__ __forceinline__ short f2bf(float f) {
  union { float f; uint32_t u; } v; v.f = f;
  uint32_t r = (v.u + 0x7FFFu + ((v.u >> 16) & 1u)) >> 16;
  return (short)(uint16_t)r;
}
static __device__ __forceinline__ float bf2f(short s) {
  union { uint32_t u; float f; } v; v.u = ((uint32_t)(uint16_t)s) << 16;
  return v.f;
}

// async global->LDS, 16B per lane, wave-uniform LDS base (lane i -> base + 16*i)
__device__ __forceinline__ void gload16(const void* g, void* l) {
  __builtin_amdgcn_global_load_lds((const __attribute__((address_space(1))) void*)g,
                                   (__attribute__((address_space(3))) void*)l,
                                   16, 0, 0);
}

// ---------------- weight fp32 -> bf16 (plain) ----------------
__global__ __launch_bounds__(256) void k_cvt_w(const float* __restrict__ src,
                                               short* __restrict__ dst, int n) {
  int i = (blockIdx.x * 256 + threadIdx.x) * 4;
  if (i + 3 < n) {
    f32x4 v = *(const f32x4*)(src + i);
    short4v o;
    o[0] = f2bf(v[0]); o[1] = f2bf(v[1]); o[2] = f2bf(v[2]); o[3] = f2bf(v[3]);
    *(short4v*)(dst + i) = o;
  }
}

// ---------------- weight fp32 -> bf16 into stacked wqkv[ax][{q,k,v}][256][256] ----------------
__global__ __launch_bounds__(256) void k_cvt_stackw(const float* __restrict__ src,
                                                    short* __restrict__ dst, int matoff) {
  int i = (blockIdx.x * 256 + threadIdx.x) * 4;
  if (i < 196608) {
    int ax = i >> 16;
    int rem = i & 65535;
    f32x4 v = *(const f32x4*)(src + i);
    short4v o;
    o[0] = f2bf(v[0]); o[1] = f2bf(v[1]); o[2] = f2bf(v[2]); o[3] = f2bf(v[3]);
    *(short4v*)(dst + ax * 196608 + matoff + rem) = o;
  }
}

// ---------------- x[b][c][p] fp32 -> h[b][p][c] bf16 ----------------
__global__ __launch_bounds__(256) void k_tin(const float* __restrict__ x,
                                             short* __restrict__ hb) {
  __shared__ float tile[64][65];  // [c][p]
  int p0 = blockIdx.x * 64, c0 = blockIdx.y * 64, b = blockIdx.z;
  int tid = threadIdx.x;
  int tx = tid & 63, tr = tid >> 6;
  const float* xp = x + ((size_t)b * CCH + c0) * PSP + p0;
  #pragma unroll
  for (int it = 0; it < 16; ++it) {
    int c = it * 4 + tr;
    tile[c][tx] = xp[(size_t)c * PSP + tx];
  }
  __syncthreads();
  short* hp = hb + ((size_t)b * PSP + p0) * CCH + c0;
  #pragma unroll
  for (int it = 0; it < 4; ++it) {
    int slot = it * 256 + tid;        // 1024 slots: p(64) x c4(16)
    int p = slot >> 4, c4 = (slot & 15) * 4;
    short4v o;
    #pragma unroll
    for (int k = 0; k < 4; ++k) o[k] = f2bf(tile[c4 + k][p]);
    *(short4v*)(hp + (size_t)p * CCH + c4) = o;
  }
}

// ---------------- fused QKV GEMM: C[131072,768] = H[131072,256] x Wqkv[768,256]^T ----------------
// m97 structure: 128x128 tile, BK=64, global_load_lds w16 with inverse-swizzled source,
// XOR-swizzled ds_read_b128, 2 barriers per k-step, LDS-staged coalesced epilogue.
__global__ __launch_bounds__(256) void k_gemm(const short* __restrict__ hb,
    const short* __restrict__ wqkv,
    short* __restrict__ qb, short* __restrict__ kb, short* __restrict__ vb)
{
  __shared__ short sm[2][8192];  // [A|B][128 rows x 64 k] bf16, 16KB each
  int tid = threadIdx.x, lane = tid & 63, w = tid >> 6, g = lane >> 4, lm = lane & 15;
  int bm = blockIdx.x, bn = blockIdx.y;
  size_t m0 = (size_t)bm * 128;
  int n0 = bn * 128;
  int wtok = (w >> 1) * 64, wco = (w & 1) * 64;

  f32x4 acc[4][4];
  #pragma unroll
  for (int i = 0; i < 4; ++i)
    #pragma unroll
    for (int j = 0; j < 4; ++j) { acc[i][j][0]=0.f; acc[i][j][1]=0.f; acc[i][j][2]=0.f; acc[i][j][3]=0.f; }

  const short* Ag = hb + m0 * 256;
  const short* Bg = wqkv + (size_t)n0 * 256;

  #pragma unroll
  for (int kt = 0; kt < 4; ++kt) {
    int k0 = kt * 64;
    // stage A tile (tokens) and B tile (weights): linear LDS dest, swizzled source
    #pragma unroll
    for (int q = 0; q < 4; ++q) {
      int s = (w * 4 + q) * 64 + lane;  // 16B-chunk slot
      int row = s >> 3, ch = s & 7;
      int sc = ch ^ (row & 7);
      gload16(Ag + (size_t)row * 256 + k0 + sc * 8, &sm[0][(w * 4 + q) * 512]);
    }
    #pragma unroll
    for (int q = 0; q < 4; ++q) {
      int s = (w * 4 + q) * 64 + lane;
      int row = s >> 3, ch = s & 7;
      int sc = ch ^ (row & 7);
      gload16(Bg + (size_t)row * 256 + k0 + sc * 8, &sm[1][(w * 4 + q) * 512]);
    }
    __syncthreads();  // drains vmcnt -> staged data visible to all waves
    #pragma unroll
    for (int ks = 0; ks < 2; ++ks) {
      bf16x8 af[4], bfr[4];
      #pragma unroll
      for (int i = 0; i < 4; ++i) {
        int r = wco + i * 16 + lm;
        af[i] = *(const bf16x8*)(&sm[1][r * 64 + (((ks * 4 + g) ^ (r & 7)) * 8)]);
      }
      #pragma unroll
      for (int j = 0; j < 4; ++j) {
        int r = wtok + j * 16 + lm;
        bfr[j] = *(const bf16x8*)(&sm[0][r * 64 + (((ks * 4 + g) ^ (r & 7)) * 8)]);
      }
      #pragma unroll
      for (int i = 0; i < 4; ++i)
        #pragma unroll
        for (int j = 0; j < 4; ++j)
          acc[i][j] = __builtin_amdgcn_mfma_f32_16x16x32_bf16(af[i], bfr[j], acc[i][j], 0, 0, 0);
    }
    __syncthreads();  // all reads done before next stage overwrites
  }

  // epilogue: acc -> swizzled LDS C tile [128 tok][128 co] bf16 (32KB), then coalesced stores
  short* ct = &sm[0][0];
  #pragma unroll
  for (int i = 0; i < 4; ++i) {
    int co = wco + i * 16 + g * 4;
    int chunk = co >> 3, off = co & 7;
    #pragma unroll
    for (int j = 0; j < 4; ++j) {
      int row = wtok + j * 16 + lm;
      short4v o;
      o[0] = f2bf(acc[i][j][0]); o[1] = f2bf(acc[i][j][1]);
      o[2] = f2bf(acc[i][j][2]); o[3] = f2bf(acc[i][j][3]);
      *(short4v*)(ct + row * 128 + ((chunk ^ (row & 7)) * 8) + off) = o;
    }
  }
  __syncthreads();

  int mat = bn >> 1;
  short* dmat = (mat == 0) ? qb : (mat == 1) ? kb : vb;
  int cbase = (bn & 1) * 128;
  #pragma unroll
  for (int it = 0; it < 8; ++it) {
    int idx = it * 256 + tid;          // 2048 chunks of 16B
    int row = idx >> 4, ch = idx & 15;
    bf16x8 v = *(const bf16x8*)(ct + row * 128 + (((ch & 8) | ((ch & 7) ^ (row & 7))) * 8));
    *(bf16x8*)(dmat + (m0 + row) * 256 + cbase + ch * 8) = v;
  }
}

// ---------------- fused attention + output projection ----------------
template<int L>
__global__ __launch_bounds__(256) void k_att(const short* __restrict__ qb,
    const short* __restrict__ kb, const short* __restrict__ vb,
    const short* __restrict__ wo, short* __restrict__ ob,
    int mulA, int mulB, int stride, int rmw)
{
  constexpr int NI = L / 16;
  constexpr int KS = (L == 64) ? 2 : 1;
  constexpr int VBYTES = 4 * L * 72 * 2;
  constexpr int OBYTES = L * 264 * 2;
  __shared__ char lds[(VBYTES > OBYTES) ? VBYTES : OBYTES];

  int tid = threadIdx.x, lane = tid & 63, w = tid >> 6, g = lane >> 4, lm = lane & 15;
  int s = blockIdx.x, b = blockIdx.y;
  size_t base = (size_t)b * PSP + (size_t)(s >> 6) * mulA + (size_t)(s & 63) * mulB;

  short* vw = (short*)lds + w * L * 72;
  if (L == 64) {
    const short* vrow = vb + (base + (size_t)lane * stride) * 256 + w * 64;
    #pragma unroll
    for (int j = 0; j < 8; ++j)
      *(bf16x8*)&vw[lane * 72 + j * 8] = *(const bf16x8*)(vrow + j * 8);
  } else {
    const short* vrow = vb + (base + (size_t)lm * stride) * 256 + w * 64 + g * 16;
    #pragma unroll
    for (int j = 0; j < 2; ++j)
      *(bf16x8*)&vw[lm * 72 + g * 16 + j * 8] = *(const bf16x8*)(vrow + j * 8);
  }
  __syncthreads();

  const short* qh = qb + base * 256 + w * 64;
  const short* kh = kb + base * 256 + w * 64;
  f32x4 t[NI][NI];
  #pragma unroll
  for (int i = 0; i < NI; ++i)
    #pragma unroll
    for (int j = 0; j < NI; ++j) { t[i][j][0]=0.f; t[i][j][1]=0.f; t[i][j][2]=0.f; t[i][j][3]=0.f; }
  #pragma unroll
  for (int ks = 0; ks < 2; ++ks) {
    bf16x8 af[NI], bq[NI];
    #pragma unroll
    for (int i = 0; i < NI; ++i)
      af[i] = *(const bf16x8*)(kh + (size_t)(i * 16 + lm) * stride * 256 + ks * 32 + g * 8);
    #pragma unroll
    for (int i = 0; i < NI; ++i)
      bq[i] = *(const bf16x8*)(qh + (size_t)(i * 16 + lm) * stride * 256 + ks * 32 + g * 8);
    #pragma unroll
    for (int mi = 0; mi < NI; ++mi)
      #pragma unroll
      for (int lj = 0; lj < NI; ++lj)
        t[mi][lj] = __builtin_amdgcn_mfma_f32_16x16x32_bf16(af[mi], bq[lj], t[mi][lj], 0, 0, 0);
  }

  const float fac = 0.18033688011112042f;  // (1/8) * log2(e)
  float inv[NI];
  #pragma unroll
  for (int lj = 0; lj < NI; ++lj) {
    float mx = -3.0e38f;
    #pragma unroll
    for (int mi = 0; mi < NI; ++mi)
      #pragma unroll
      for (int r = 0; r < 4; ++r) mx = fmaxf(mx, t[mi][lj][r]);
    mx = fmaxf(mx, __shfl_xor(mx, 16));
    mx = fmaxf(mx, __shfl_xor(mx, 32));
    float sm = 0.f;
    #pragma unroll
    for (int mi = 0; mi < NI; ++mi)
      #pragma unroll
      for (int r = 0; r < 4; ++r) {
        float e = exp2f((t[mi][lj][r] - mx) * fac);
        t[mi][lj][r] = e; sm += e;
      }
    sm += __shfl_xor(sm, 16);
    sm += __shfl_xor(sm, 32);
    inv[lj] = 1.0f / sm;
  }

  bf16x8 pa[NI][KS];
  #pragma unroll
  for (int lj = 0; lj < NI; ++lj)
    #pragma unroll
    for (int ks = 0; ks < KS; ++ks) {
      bf16x8 a;
      #pragma unroll
      for (int j = 0; j < 8; ++j) {
        int mi = ks * 2 + (j >> 2);
        float v = (mi < NI) ? t[mi][lj][j & 3] * inv[lj] : 0.f;
        a[j] = f2bf(v);
      }
      pa[lj][ks] = a;
    }

  f32x4 oa[NI][4];
  #pragma unroll
  for (int i = 0; i < NI; ++i)
    #pragma unroll
    for (int j = 0; j < 4; ++j) { oa[i][j][0]=0.f; oa[i][j][1]=0.f; oa[i][j][2]=0.f; oa[i][j][3]=0.f; }
  #pragma unroll
  for (int ks = 0; ks < KS; ++ks)
    #pragma unroll
    for (int ej = 0; ej < 4; ++ej) {
      bf16x8 bv;
      int e = ej * 16 + lm;
      int rb = ks * 32 + g * 4;
      #pragma unroll
      for (int j = 0; j < 4; ++j) bv[j] = vw[(rb + j) * 72 + e];
      if (L == 64) {
        #pragma unroll
        for (int j = 0; j < 4; ++j) bv[4 + j] = vw[(rb + 16 + j) * 72 + e];
      } else {
        #pragma unroll
        for (int j = 0; j < 4; ++j) bv[4 + j] = 0;
      }
      #pragma unroll
      for (int lj = 0; lj < NI; ++lj)
        oa[lj][ej] = __builtin_amdgcn_mfma_f32_16x16x32_bf16(pa[lj][ks], bv, oa[lj][ej], 0, 0, 0);
    }

  __syncthreads();
  short* ot = (short*)lds;  // [L][264]
  #pragma unroll
  for (int lj = 0; lj < NI; ++lj)
    #pragma unroll
    for (int ej = 0; ej < 4; ++ej)
      #pragma unroll
      for (int r = 0; r < 4; ++r)
        ot[(lj * 16 + g * 4 + r) * 264 + w * 64 + ej * 16 + lm] = f2bf(oa[lj][ej][r]);
  __syncthreads();

  constexpr int NIF = (L == 64) ? 16 : 4;
  int if0 = (L == 64) ? 0 : (w * 4);
  int tw  = (L == 64) ? (w * 16) : 0;
  f32x4 pacc[NIF];
  #pragma unroll
  for (int i = 0; i < NIF; ++i) { pacc[i][0]=0.f; pacc[i][1]=0.f; pacc[i][2]=0.f; pacc[i][3]=0.f; }
  #pragma unroll
  for (int ks = 0; ks < 8; ++ks) {
    bf16x8 bo_ = *(const bf16x8*)&ot[(tw + lm) * 264 + ks * 32 + g * 8];
    #pragma unroll
    for (int i = 0; i < NIF; ++i) {
      bf16x8 af = *(const bf16x8*)(wo + (size_t)((if0 + i) * 16 + lm) * 256 + ks * 32 + g * 8);
      pacc[i] = __builtin_amdgcn_mfma_f32_16x16x32_bf16(af, bo_, pacc[i], 0, 0, 0);
    }
  }
  size_t tokr = base + (size_t)(tw + lm) * stride;
  short* dst0 = ob + tokr * 256;
  #pragma unroll
  for (int i = 0; i < NIF; ++i) {
    int co = (if0 + i) * 16 + g * 4;
    float v0 = pacc[i][0], v1 = pacc[i][1], v2 = pacc[i][2], v3 = pacc[i][3];
    if (rmw) {
      short4v old = *(short4v*)(dst0 + co);
      v0 += bf2f(old[0]); v1 += bf2f(old[1]); v2 += bf2f(old[2]); v3 += bf2f(old[3]);
    }
    short4v o;
    o[0] = f2bf(v0); o[1] = f2bf(v1); o[2] = f2bf(v2); o[3] = f2bf(v3);
    *(short4v*)(dst0 + co) = o;
  }
}

// ---------------- out[b][c][p] = o0[b][p][c] + o1[b][p][c] + sum(bias) ----------------
__global__ __launch_bounds__(256) void k_final(const short* __restrict__ o0,
                                               const short* __restrict__ o1,
                                               const float* __restrict__ bo,
                                               float* __restrict__ out) {
  __shared__ float tile[64][65];  // [c][p]
  __shared__ float bias[64];
  int p0 = blockIdx.x * 64, c0 = blockIdx.y * 64, b = blockIdx.z;
  int tid = threadIdx.x;
  if (tid < 64)
    bias[tid] = bo[c0 + tid] + bo[256 + c0 + tid] + bo[512 + c0 + tid];
  const short* a0 = o0 + ((size_t)b * PSP + p0) * CCH + c0;
  const short* a1 = o1 + ((size_t)b * PSP + p0) * CCH + c0;
  #pragma unroll
  for (int it = 0; it < 4; ++it) {
    int slot = it * 256 + tid;
    int p = slot >> 4, c4 = (slot & 15) * 4;
    short4v v0 = *(const short4v*)(a0 + (size_t)p * CCH + c4);
    short4v v1 = *(const short4v*)(a1 + (size_t)p * CCH + c4);
    #pragma unroll
    for (int j = 0; j < 4; ++j)
      tile[c4 + j][p] = bf2f(v0[j]) + bf2f(v1[j]);
  }
  __syncthreads();
  float* op = out + ((size_t)b * CCH + c0) * PSP + p0;
  int tx = tid & 63, tr = tid >> 6;
  #pragma unroll
  for (int it = 0; it < 16; ++it) {
    int c = it * 4 + tr;
    op[(size_t)c * PSP + tx] = tile[c][tx] + bias[c];
  }
}

extern "C" void kernel_launch(void* const* d_in, const int* in_sizes, int n_in,
                              void* d_out, int out_size, void* d_ws, size_t ws_size,
                              hipStream_t stream) {
  const float* x  = (const float*)d_in[0];
  const float* Wq = (const float*)d_in[1];
  const float* Wk = (const float*)d_in[2];
  const float* Wv = (const float*)d_in[3];
  const float* Wo = (const float*)d_in[4];
  const float* bo = (const float*)d_in[5];
  float* out = (float*)d_out;

  char* ws = (char*)d_ws;
  size_t off = 0;
  auto alloc = [&](size_t bytes) -> char* {
    char* p = ws + off;
    off += (bytes + 255) & ~(size_t)255;
    return p;
  };
  short* wqkv = (short*)alloc((size_t)3 * 196608 * 2);  // [ax][{q,k,v}][256][256]
  short* wob  = (short*)alloc((size_t)3 * 65536 * 2);
  short* hb   = (short*)alloc((size_t)NTOK * 256 * 2);
  short* qbuf = (short*)alloc((size_t)NTOK * 256 * 2);
  short* kbuf = (short*)alloc((size_t)NTOK * 256 * 2);
  short* vbuf = (short*)alloc((size_t)NTOK * 256 * 2);
  short* o0   = (short*)alloc((size_t)NTOK * 256 * 2);
  short* o1   = (short*)alloc((size_t)NTOK * 256 * 2);
  if (off > ws_size) return;  // workspace too small

  k_cvt_stackw<<<192, 256, 0, stream>>>(Wq, wqkv, 0);
  k_cvt_stackw<<<192, 256, 0, stream>>>(Wk, wqkv, 65536);
  k_cvt_stackw<<<192, 256, 0, stream>>>(Wv, wqkv, 131072);
  k_cvt_w<<<192, 256, 0, stream>>>(Wo, wob, 196608);
  k_tin<<<dim3(1024, 4, 2), 256, 0, stream>>>(x, hb);

  for (int ax = 0; ax < 3; ++ax) {
    k_gemm<<<dim3(1024, 6), 256, 0, stream>>>(hb, wqkv + (size_t)ax * 196608,
                                              qbuf, kbuf, vbuf);
    if (ax == 0)
      k_att<16><<<dim3(4096, 2), 256, 0, stream>>>(qbuf, kbuf, vbuf, wob, o0,
                                                   64, 1, 4096, 0);
    else if (ax == 1)
      k_att<64><<<dim3(1024, 2), 256, 0, stream>>>(qbuf, kbuf, vbuf, wob + 65536, o1,
                                                   4096, 1, 64, 0);
    else
      k_att<64><<<dim3(1024, 2), 256, 0, stream>>>(qbuf, kbuf, vbuf, wob + 131072, o1,
                                                   4096, 64, 1, 1);
  }
  k_final<<<dim3(1024, 4, 2), 256, 0, stream>>>(o0, o1, bo, out);
}

// Round 4
// 933.707 us; speedup vs baseline: 2.2947x; 1.1861x over previous
//
#include <hip/hip_runtime.h>
#include <stdint.h>

typedef __attribute__((ext_vector_type(8))) short bf16x8;
typedef __attribute__((ext_vector_type(4))) short short4v;
typedef __attribute__((ext_vector_type(4))) float f32x4;

#define CCH  256
#define PSP  65536
#define NTOK 131072

static __device__ __forceinline__ short f2bf(float f) {
  union { float f; uint32_t u; } v; v.f = f;
  uint32_t r = (v.u + 0x7FFFu + ((v.u >> 16) & 1u)) >> 16;
  return (short)(uint16_t)r;
}
static __device__ __forceinline__ float bf2f(short s) {
  union { uint32_t u; float f; } v; v.u = ((uint32_t)(uint16_t)s) << 16;
  return v.f;
}

// async global->LDS, 16B per lane, wave-uniform LDS base (lane i -> base + 16*i)
__device__ __forceinline__ void gload16(const void* g, void* l) {
  __builtin_amdgcn_global_load_lds((const __attribute__((address_space(1))) void*)g,
                                   (__attribute__((address_space(3))) void*)l,
                                   16, 0, 0);
}

// ---------------- weight fp32 -> bf16 (plain) ----------------
__global__ __launch_bounds__(256) void k_cvt_w(const float* __restrict__ src,
                                               short* __restrict__ dst, int n) {
  int i = (blockIdx.x * 256 + threadIdx.x) * 4;
  if (i + 3 < n) {
    f32x4 v = *(const f32x4*)(src + i);
    short4v o;
    o[0] = f2bf(v[0]); o[1] = f2bf(v[1]); o[2] = f2bf(v[2]); o[3] = f2bf(v[3]);
    *(short4v*)(dst + i) = o;
  }
}

// ---------------- weight fp32 -> bf16 into stacked wqkv[ax][{q,k,v}][256][256] ----------------
__global__ __launch_bounds__(256) void k_cvt_stackw(const float* __restrict__ src,
                                                    short* __restrict__ dst, int matoff) {
  int i = (blockIdx.x * 256 + threadIdx.x) * 4;
  if (i < 196608) {
    int ax = i >> 16;
    int rem = i & 65535;
    f32x4 v = *(const f32x4*)(src + i);
    short4v o;
    o[0] = f2bf(v[0]); o[1] = f2bf(v[1]); o[2] = f2bf(v[2]); o[3] = f2bf(v[3]);
    *(short4v*)(dst + ax * 196608 + matoff + rem) = o;
  }
}

// ---------------- x[b][c][p] fp32 -> h[b][p][c] bf16 ----------------
__global__ __launch_bounds__(256) void k_tin(const float* __restrict__ x,
                                             short* __restrict__ hb) {
  __shared__ float tile[64][65];  // [c][p]
  int p0 = blockIdx.x * 64, c0 = blockIdx.y * 64, b = blockIdx.z;
  int tid = threadIdx.x;
  int tx = tid & 63, tr = tid >> 6;
  const float* xp = x + ((size_t)b * CCH + c0) * PSP + p0;
  #pragma unroll
  for (int it = 0; it < 16; ++it) {
    int c = it * 4 + tr;
    tile[c][tx] = xp[(size_t)c * PSP + tx];
  }
  __syncthreads();
  short* hp = hb + ((size_t)b * PSP + p0) * CCH + c0;
  #pragma unroll
  for (int it = 0; it < 4; ++it) {
    int slot = it * 256 + tid;        // 1024 slots: p(64) x c4(16)
    int p = slot >> 4, c4 = (slot & 15) * 4;
    short4v o;
    #pragma unroll
    for (int k = 0; k < 4; ++k) o[k] = f2bf(tile[c4 + k][p]);
    *(short4v*)(hp + (size_t)p * CCH + c4) = o;
  }
}

// ---------------- fused QKV GEMM: C[131072,768] = H[131072,256] x Wqkv[768,256]^T ----------------
__global__ __launch_bounds__(256) void k_gemm(const short* __restrict__ hb,
    const short* __restrict__ wqkv,
    short* __restrict__ qb, short* __restrict__ kb, short* __restrict__ vb)
{
  __shared__ short sm[2][8192];  // [A|B][128 rows x 64 k] bf16, 16KB each
  int tid = threadIdx.x, lane = tid & 63, w = tid >> 6, g = lane >> 4, lm = lane & 15;
  int bm = blockIdx.x, bn = blockIdx.y;
  size_t m0 = (size_t)bm * 128;
  int n0 = bn * 128;
  int wtok = (w >> 1) * 64, wco = (w & 1) * 64;

  f32x4 acc[4][4];
  #pragma unroll
  for (int i = 0; i < 4; ++i)
    #pragma unroll
    for (int j = 0; j < 4; ++j) { acc[i][j][0]=0.f; acc[i][j][1]=0.f; acc[i][j][2]=0.f; acc[i][j][3]=0.f; }

  const short* Ag = hb + m0 * 256;
  const short* Bg = wqkv + (size_t)n0 * 256;

  #pragma unroll
  for (int kt = 0; kt < 4; ++kt) {
    int k0 = kt * 64;
    #pragma unroll
    for (int q = 0; q < 4; ++q) {
      int s = (w * 4 + q) * 64 + lane;  // 16B-chunk slot
      int row = s >> 3, ch = s & 7;
      int sc = ch ^ (row & 7);
      gload16(Ag + (size_t)row * 256 + k0 + sc * 8, &sm[0][(w * 4 + q) * 512]);
    }
    #pragma unroll
    for (int q = 0; q < 4; ++q) {
      int s = (w * 4 + q) * 64 + lane;
      int row = s >> 3, ch = s & 7;
      int sc = ch ^ (row & 7);
      gload16(Bg + (size_t)row * 256 + k0 + sc * 8, &sm[1][(w * 4 + q) * 512]);
    }
    __syncthreads();
    #pragma unroll
    for (int ks = 0; ks < 2; ++ks) {
      bf16x8 af[4], bfr[4];
      #pragma unroll
      for (int i = 0; i < 4; ++i) {
        int r = wco + i * 16 + lm;
        af[i] = *(const bf16x8*)(&sm[1][r * 64 + (((ks * 4 + g) ^ (r & 7)) * 8)]);
      }
      #pragma unroll
      for (int j = 0; j < 4; ++j) {
        int r = wtok + j * 16 + lm;
        bfr[j] = *(const bf16x8*)(&sm[0][r * 64 + (((ks * 4 + g) ^ (r & 7)) * 8)]);
      }
      #pragma unroll
      for (int i = 0; i < 4; ++i)
        #pragma unroll
        for (int j = 0; j < 4; ++j)
          acc[i][j] = __builtin_amdgcn_mfma_f32_16x16x32_bf16(af[i], bfr[j], acc[i][j], 0, 0, 0);
    }
    __syncthreads();
  }

  short* ct = &sm[0][0];
  #pragma unroll
  for (int i = 0; i < 4; ++i) {
    int co = wco + i * 16 + g * 4;
    int chunk = co >> 3, off = co & 7;
    #pragma unroll
    for (int j = 0; j < 4; ++j) {
      int row = wtok + j * 16 + lm;
      short4v o;
      o[0] = f2bf(acc[i][j][0]); o[1] = f2bf(acc[i][j][1]);
      o[2] = f2bf(acc[i][j][2]); o[3] = f2bf(acc[i][j][3]);
      *(short4v*)(ct + row * 128 + ((chunk ^ (row & 7)) * 8) + off) = o;
    }
  }
  __syncthreads();

  int mat = bn >> 1;
  short* dmat = (mat == 0) ? qb : (mat == 1) ? kb : vb;
  int cbase = (bn & 1) * 128;
  #pragma unroll
  for (int it = 0; it < 8; ++it) {
    int idx = it * 256 + tid;          // 2048 chunks of 16B
    int row = idx >> 4, ch = idx & 15;
    bf16x8 v = *(const bf16x8*)(ct + row * 128 + (((ch & 8) | ((ch & 7) ^ (row & 7))) * 8));
    *(bf16x8*)(dmat + (m0 + row) * 256 + cbase + ch * 8) = v;
  }
}

// ---------------- fused attention + output projection (restructured) ----------------
// Block = one sequence, wave = head for attention; wave = co-range [64w,64w+64)
// for the Wo projection (4x less Wo per wave). PV computed as O^T = V^T P with
// shared k-permutation sigma(g,j)=32ks+16(j>>2)+4g+(j&3) on both operands:
// conflict-free LDS reads, vectorized ot writes. No barrier before QK^T (waves
// read only their own V region). V+K/Q loads issued together -> 1 HBM round trip.
template<int L>
__global__ __launch_bounds__(256) void k_att(const short* __restrict__ qb,
    const short* __restrict__ kb, const short* __restrict__ vb,
    const short* __restrict__ wo, short* __restrict__ ob,
    int mulA, int mulB, int stride, int rmw)
{
  constexpr int NI = L / 16;
  constexpr int KS = (L == 64) ? 2 : 1;
  constexpr int NV = (L == 64) ? 8 : 2;
  constexpr int VBYTES = 4 * L * 72 * 2;
  constexpr int OBYTES = L * 264 * 2;
  __shared__ char lds[(VBYTES > OBYTES) ? VBYTES : OBYTES];

  int tid = threadIdx.x, lane = tid & 63, w = tid >> 6, g = lane >> 4, lm = lane & 15;
  int s = blockIdx.x, b = blockIdx.y;
  size_t base = (size_t)b * PSP + (size_t)(s >> 6) * mulA + (size_t)(s & 63) * mulB;

  short* vw = (short*)lds + w * L * 72;  // this wave's V tile [L][72]

  // ---- issue V loads (registers), then K/Q ks=0 loads: one merged HBM trip ----
  bf16x8 vr[NV];
  if (L == 64) {
    const short* vrow = vb + (base + (size_t)lane * stride) * 256 + w * 64;
    #pragma unroll
    for (int j = 0; j < NV; ++j) vr[j] = *(const bf16x8*)(vrow + j * 8);
  } else {
    const short* vrow = vb + (base + (size_t)lm * stride) * 256 + w * 64 + g * 16;
    #pragma unroll
    for (int j = 0; j < NV; ++j) vr[j] = *(const bf16x8*)(vrow + j * 8);
  }
  const short* qh = qb + base * 256 + w * 64;
  const short* kh = kb + base * 256 + w * 64;
  bf16x8 af0[NI], bq0[NI];
  #pragma unroll
  for (int i = 0; i < NI; ++i)
    af0[i] = *(const bf16x8*)(kh + (size_t)(i * 16 + lm) * stride * 256 + g * 8);
  #pragma unroll
  for (int i = 0; i < NI; ++i)
    bq0[i] = *(const bf16x8*)(qh + (size_t)(i * 16 + lm) * stride * 256 + g * 8);

  // ---- V -> LDS (own-wave region; no cross-wave barrier needed) ----
  if (L == 64) {
    #pragma unroll
    for (int j = 0; j < NV; ++j) *(bf16x8*)&vw[lane * 72 + j * 8] = vr[j];
  } else {
    #pragma unroll
    for (int j = 0; j < NV; ++j) *(bf16x8*)&vw[lm * 72 + g * 16 + j * 8] = vr[j];
  }

  // ---- T = K Q^T, ks=0 then ks=1 ----
  f32x4 t[NI][NI];
  #pragma unroll
  for (int i = 0; i < NI; ++i)
    #pragma unroll
    for (int j = 0; j < NI; ++j) { t[i][j][0]=0.f; t[i][j][1]=0.f; t[i][j][2]=0.f; t[i][j][3]=0.f; }
  #pragma unroll
  for (int mi = 0; mi < NI; ++mi)
    #pragma unroll
    for (int lj = 0; lj < NI; ++lj)
      t[mi][lj] = __builtin_amdgcn_mfma_f32_16x16x32_bf16(af0[mi], bq0[lj], t[mi][lj], 0, 0, 0);
  {
    bf16x8 af1[NI], bq1[NI];
    #pragma unroll
    for (int i = 0; i < NI; ++i)
      af1[i] = *(const bf16x8*)(kh + (size_t)(i * 16 + lm) * stride * 256 + 32 + g * 8);
    #pragma unroll
    for (int i = 0; i < NI; ++i)
      bq1[i] = *(const bf16x8*)(qh + (size_t)(i * 16 + lm) * stride * 256 + 32 + g * 8);
    #pragma unroll
    for (int mi = 0; mi < NI; ++mi)
      #pragma unroll
      for (int lj = 0; lj < NI; ++lj)
        t[mi][lj] = __builtin_amdgcn_mfma_f32_16x16x32_bf16(af1[mi], bq1[lj], t[mi][lj], 0, 0, 0);
  }

  // ---- softmax over ktok (rows), per qtok column lj/lm ----
  const float fac = 0.18033688011112042f;  // (1/8) * log2(e)
  float inv[NI];
  #pragma unroll
  for (int lj = 0; lj < NI; ++lj) {
    float mx = -3.0e38f;
    #pragma unroll
    for (int mi = 0; mi < NI; ++mi)
      #pragma unroll
      for (int r = 0; r < 4; ++r) mx = fmaxf(mx, t[mi][lj][r]);
    mx = fmaxf(mx, __shfl_xor(mx, 16));
    mx = fmaxf(mx, __shfl_xor(mx, 32));
    float sm = 0.f;
    #pragma unroll
    for (int mi = 0; mi < NI; ++mi)
      #pragma unroll
      for (int r = 0; r < 4; ++r) {
        float e = exp2f((t[mi][lj][r] - mx) * fac);
        t[mi][lj][r] = e; sm += e;
      }
    sm += __shfl_xor(sm, 16);
    sm += __shfl_xor(sm, 32);
    inv[lj] = 1.0f / sm;
  }

  // ---- pack P as B-fragments with k-permutation sigma ----
  bf16x8 pb[NI][KS];
  #pragma unroll
  for (int lj = 0; lj < NI; ++lj)
    #pragma unroll
    for (int ks = 0; ks < KS; ++ks) {
      bf16x8 a;
      #pragma unroll
      for (int j = 0; j < 8; ++j) {
        int mi = ks * 2 + (j >> 2);
        float v = (mi < NI) ? t[mi][lj][j & 3] * inv[lj] : 0.f;
        a[j] = f2bf(v);
      }
      pb[lj][ks] = a;
    }

  // ---- O^T = V^T P : A-frag = V with sigma rows (conflict-free), B-frag = pb ----
  f32x4 oa[4][NI];
  #pragma unroll
  for (int ej = 0; ej < 4; ++ej)
    #pragma unroll
    for (int lj = 0; lj < NI; ++lj) { oa[ej][lj][0]=0.f; oa[ej][lj][1]=0.f; oa[ej][lj][2]=0.f; oa[ej][lj][3]=0.f; }
  #pragma unroll
  for (int ks = 0; ks < KS; ++ks)
    #pragma unroll
    for (int ej = 0; ej < 4; ++ej) {
      bf16x8 vf;
      #pragma unroll
      for (int j = 0; j < 8; ++j) {
        if (L == 16 && j >= 4) { vf[j] = 0; }
        else {
          int row = ks * 32 + 16 * (j >> 2) + 4 * g + (j & 3);
          vf[j] = vw[row * 72 + ej * 16 + lm];
        }
      }
      #pragma unroll
      for (int lj = 0; lj < NI; ++lj)
        oa[ej][lj] = __builtin_amdgcn_mfma_f32_16x16x32_bf16(vf, pb[lj][ks], oa[ej][lj], 0, 0, 0);
    }

  __syncthreads();  // all waves done reading their V; alias LDS as ot
  short* ot = (short*)lds;  // [L][264] row-major [token][ch]
  #pragma unroll
  for (int ej = 0; ej < 4; ++ej)
    #pragma unroll
    for (int lj = 0; lj < NI; ++lj) {
      short4v o;
      #pragma unroll
      for (int r = 0; r < 4; ++r) o[r] = f2bf(oa[ej][lj][r]);
      *(short4v*)&ot[(lj * 16 + lm) * 264 + w * 64 + ej * 16 + g * 4] = o;
    }
  __syncthreads();

  // ---- Wo projection, co-split: wave w -> co in [64w, 64w+64), all tokens ----
  f32x4 pacc[4][NI];
  #pragma unroll
  for (int i = 0; i < 4; ++i)
    #pragma unroll
    for (int j = 0; j < NI; ++j) { pacc[i][j][0]=0.f; pacc[i][j][1]=0.f; pacc[i][j][2]=0.f; pacc[i][j][3]=0.f; }
  #pragma unroll
  for (int ks = 0; ks < 8; ++ks) {
    bf16x8 bfr[NI];
    #pragma unroll
    for (int j = 0; j < NI; ++j)
      bfr[j] = *(const bf16x8*)&ot[(j * 16 + lm) * 264 + ks * 32 + g * 8];
    #pragma unroll
    for (int i = 0; i < 4; ++i) {
      bf16x8 afr = *(const bf16x8*)(wo + (size_t)(w * 64 + i * 16 + lm) * 256 + ks * 32 + g * 8);
      #pragma unroll
      for (int j = 0; j < NI; ++j)
        pacc[i][j] = __builtin_amdgcn_mfma_f32_16x16x32_bf16(afr, bfr[j], pacc[i][j], 0, 0, 0);
    }
  }
  #pragma unroll
  for (int j = 0; j < NI; ++j) {
    size_t tokr = base + (size_t)(j * 16 + lm) * stride;
    short* dst0 = ob + tokr * 256 + w * 64;
    #pragma unroll
    for (int i = 0; i < 4; ++i) {
      int co = i * 16 + g * 4;
      float v0 = pacc[i][j][0], v1 = pacc[i][j][1], v2 = pacc[i][j][2], v3 = pacc[i][j][3];
      if (rmw) {
        short4v old = *(short4v*)(dst0 + co);
        v0 += bf2f(old[0]); v1 += bf2f(old[1]); v2 += bf2f(old[2]); v3 += bf2f(old[3]);
      }
      short4v o;
      o[0] = f2bf(v0); o[1] = f2bf(v1); o[2] = f2bf(v2); o[3] = f2bf(v3);
      *(short4v*)(dst0 + co) = o;
    }
  }
}

// ---------------- out[b][c][p] = o0[b][p][c] + o1[b][p][c] + sum(bias) ----------------
__global__ __launch_bounds__(256) void k_final(const short* __restrict__ o0,
                                               const short* __restrict__ o1,
                                               const float* __restrict__ bo,
                                               float* __restrict__ out) {
  __shared__ float tile[64][65];  // [c][p]
  __shared__ float bias[64];
  int p0 = blockIdx.x * 64, c0 = blockIdx.y * 64, b = blockIdx.z;
  int tid = threadIdx.x;
  if (tid < 64)
    bias[tid] = bo[c0 + tid] + bo[256 + c0 + tid] + bo[512 + c0 + tid];
  const short* a0 = o0 + ((size_t)b * PSP + p0) * CCH + c0;
  const short* a1 = o1 + ((size_t)b * PSP + p0) * CCH + c0;
  #pragma unroll
  for (int it = 0; it < 4; ++it) {
    int slot = it * 256 + tid;
    int p = slot >> 4, c4 = (slot & 15) * 4;
    short4v v0 = *(const short4v*)(a0 + (size_t)p * CCH + c4);
    short4v v1 = *(const short4v*)(a1 + (size_t)p * CCH + c4);
    #pragma unroll
    for (int j = 0; j < 4; ++j)
      tile[c4 + j][p] = bf2f(v0[j]) + bf2f(v1[j]);
  }
  __syncthreads();
  float* op = out + ((size_t)b * CCH + c0) * PSP + p0;
  int tx = tid & 63, tr = tid >> 6;
  #pragma unroll
  for (int it = 0; it < 16; ++it) {
    int c = it * 4 + tr;
    op[(size_t)c * PSP + tx] = tile[c][tx] + bias[c];
  }
}

extern "C" void kernel_launch(void* const* d_in, const int* in_sizes, int n_in,
                              void* d_out, int out_size, void* d_ws, size_t ws_size,
                              hipStream_t stream) {
  const float* x  = (const float*)d_in[0];
  const float* Wq = (const float*)d_in[1];
  const float* Wk = (const float*)d_in[2];
  const float* Wv = (const float*)d_in[3];
  const float* Wo = (const float*)d_in[4];
  const float* bo = (const float*)d_in[5];
  float* out = (float*)d_out;

  char* ws = (char*)d_ws;
  size_t off = 0;
  auto alloc = [&](size_t bytes) -> char* {
    char* p = ws + off;
    off += (bytes + 255) & ~(size_t)255;
    return p;
  };
  short* wqkv = (short*)alloc((size_t)3 * 196608 * 2);  // [ax][{q,k,v}][256][256]
  short* wob  = (short*)alloc((size_t)3 * 65536 * 2);
  short* hb   = (short*)alloc((size_t)NTOK * 256 * 2);
  short* qbuf = (short*)alloc((size_t)NTOK * 256 * 2);
  short* kbuf = (short*)alloc((size_t)NTOK * 256 * 2);
  short* vbuf = (short*)alloc((size_t)NTOK * 256 * 2);
  short* o0   = (short*)alloc((size_t)NTOK * 256 * 2);
  short* o1   = (short*)alloc((size_t)NTOK * 256 * 2);
  if (off > ws_size) return;  // workspace too small

  k_cvt_stackw<<<192, 256, 0, stream>>>(Wq, wqkv, 0);
  k_cvt_stackw<<<192, 256, 0, stream>>>(Wk, wqkv, 65536);
  k_cvt_stackw<<<192, 256, 0, stream>>>(Wv, wqkv, 131072);
  k_cvt_w<<<192, 256, 0, stream>>>(Wo, wob, 196608);
  k_tin<<<dim3(1024, 4, 2), 256, 0, stream>>>(x, hb);

  for (int ax = 0; ax < 3; ++ax) {
    k_gemm<<<dim3(1024, 6), 256, 0, stream>>>(hb, wqkv + (size_t)ax * 196608,
                                              qbuf, kbuf, vbuf);
    if (ax == 0)
      k_att<16><<<dim3(4096, 2), 256, 0, stream>>>(qbuf, kbuf, vbuf, wob, o0,
                                                   64, 1, 4096, 0);
    else if (ax == 1)
      k_att<64><<<dim3(1024, 2), 256, 0, stream>>>(qbuf, kbuf, vbuf, wob + 65536, o1,
                                                   4096, 1, 64, 0);
    else
      k_att<64><<<dim3(1024, 2), 256, 0, stream>>>(qbuf, kbuf, vbuf, wob + 131072, o1,
                                                   4096, 64, 1, 1);
  }
  k_final<<<dim3(1024, 4, 2), 256, 0, stream>>>(o0, o1, bo, out);
}